// Round 14
// baseline (212.480 us; speedup 1.0000x reference)
//
#include <hip/hip_runtime.h>

// Problem constants (z: [4, 64, 32, 32, 32] f32, embedding: [1024, 64] f32)
#define CH     64
#define KC     1024
#define SP     32768              // 32*32*32
#define NBATCH 4
#define NTOK   (NBATCH * SP)      // 131072
#define MTOK   64                 // tokens per block (R8/R12-verified)
#define SZZ    68                 // zl row stride (floats)
#define ECH    128                // codes per LDS chunk (8 chunks, R8/R12-verified)
#define NCHK   (KC / ECH)         // 8
#define CAP    16                 // MUST be 16: margin sets are often 9..16 codes; CAP<=8
                                  // routes tokens through the serial full-scan fallback
                                  // (+~400 us chip-wide — R10/R11 A/B proof)
#define MARGIN 3.0f               // > 2*eps, eps = max |d_bf16 - d_fp32| (~0.9)

// d_out flat layout (all float32): z_q, loss, perplexity, indices, mean(dist)
#define OFF_ZQ   0
#define OFF_LOSS (NBATCH * CH * SP)      // 8388608
#define OFF_PERP (OFF_LOSS + 1)
#define OFF_IDX  (OFF_PERP + 1)          // 8388610
#define OFF_MEAN (OFF_IDX + NTOK)        // 8519682

// workspace layout (32-bit words)
// [0,1024)      int   hist
// [1024]        float sum_z2
// [1025]        float sum_e2
// [1026,1090)   float sum_zc[64]
// [1090,1154)   float sum_ec[64]
// [1154,2178)   float enorm[1024]
// [4096,20480)  ushort eb[1024*64]  (bf16 embedding table, 128 KB)

typedef __attribute__((ext_vector_type(8))) short  s16x8;   // 8 bf16 (4 VGPRs)
typedef __attribute__((ext_vector_type(4))) float  f32x4;

__device__ __forceinline__ unsigned short f2bf(float f) {   // RNE, deterministic
    unsigned int u = __float_as_uint(f);
    return (unsigned short)((u + 0x7fffu + ((u >> 16) & 1u)) >> 16);
}

// frozen exact fp32 distance (bitwise identical to round 0)
__device__ __forceinline__ float exact_dist(const float* zrow,
                                            const float* __restrict__ emb,
                                            const float* __restrict__ enl, int c) {
    const float4* er = (const float4*)(emb + (size_t)c * CH);
    float a0 = 0.f, a1 = 0.f, a2 = 0.f, a3 = 0.f;
#pragma unroll
    for (int j = 0; j < 16; ++j) {
        float4 e4 = er[j];
        a0 = fmaf(zrow[4 * j + 0], e4.x, a0);
        a1 = fmaf(zrow[4 * j + 1], e4.y, a1);
        a2 = fmaf(zrow[4 * j + 2], e4.z, a2);
        a3 = fmaf(zrow[4 * j + 3], e4.w, a3);
    }
    return enl[c] - 2.f * ((a0 + a1) + (a2 + a3));
}

// prep: unchanged
__global__ __launch_bounds__(256) void prep(const float* __restrict__ e,
                                            int* __restrict__ hist,
                                            float* __restrict__ sums,
                                            float* __restrict__ sum_zc,
                                            float* __restrict__ sum_ec,
                                            float* __restrict__ enorm,
                                            unsigned short* __restrict__ eb) {
    const int tid = threadIdx.x;
    const int bk = blockIdx.x;
    if (bk < 4) {
        int k = bk * 256 + tid;
        const float4* row = (const float4*)(e + (size_t)k * CH);
        float n = 0.f;
#pragma unroll
        for (int j = 0; j < CH / 4; ++j) {
            float4 v = row[j];
            n += v.x * v.x + v.y * v.y + v.z * v.z + v.w * v.w;
        }
        enorm[k] = n;
    } else if (bk == 4) {
        if (tid == 0) sums[0] = 0.f;
        if (tid < 64) sum_zc[tid] = 0.f;
        __shared__ float ls1[256];
        __shared__ float r2[4];
        int c = tid & 63;
        int strip = tid >> 6;
        float s1 = 0.f, s2 = 0.f;
        for (int k = strip * 256; k < strip * 256 + 256; ++k) {
            float v = e[k * CH + c];
            s1 += v;
            s2 = fmaf(v, v, s2);
        }
        ls1[tid] = s1;
        for (int off = 32; off; off >>= 1) s2 += __shfl_down(s2, off);
        if ((tid & 63) == 0) r2[tid >> 6] = s2;
        __syncthreads();
        if (strip == 0) sum_ec[c] = ls1[c] + ls1[64 + c] + ls1[128 + c] + ls1[192 + c];
        if (tid == 0) sums[1] = r2[0] + r2[1] + r2[2] + r2[3];
    } else if (bk < 9) {
        hist[(bk - 5) * 256 + tid] = 0;
    } else {
        int base = (bk - 9) * 16384;
        for (int j = 0; j < 64; ++j) {
            int i = base + tid + j * 256;
            eb[i] = f2bf(e[i]);
        }
    }
}

// async global->LDS, 16 B per lane, linear wave dest. R4/R13-verified.
#define GLD16(gsrc, ldst)                                                        \
    __builtin_amdgcn_global_load_lds(                                            \
        (const __attribute__((address_space(1))) unsigned int*)(gsrc),           \
        (__attribute__((address_space(3))) unsigned int*)(ldst), 16, 0, 0)

// A-fragment builder (R10/R11-verified)
#define MK8(A, ptr)                                            \
    {                                                          \
        float4 _a = *(const float4*)(ptr);                     \
        float4 _b = *(const float4*)((ptr) + 4);               \
        A[0] = (short)f2bf(_a.x); A[1] = (short)f2bf(_a.y);    \
        A[2] = (short)f2bf(_a.z); A[3] = (short)f2bf(_a.w);    \
        A[4] = (short)f2bf(_b.x); A[5] = (short)f2bf(_b.y);    \
        A[6] = (short)f2bf(_b.z); A[7] = (short)f2bf(_b.w);    \
    }

// main: R13 kernel with CODE-QUARTERED waves: wave w owns codes [w*32,w*32+32)
// of each chunk and computes ALL 64 tokens (4 token-groups x 2 K-halves = same
// MFMA count/wave). B ds_read traffic /4. MFMA inputs unchanged -> d bitwise
// identical; bmin = min over 4 wave-partials (order-independent); candidate
// membership identical; (d,c) tie rule -> identical output. LDS 40960 (wmin
// aliased onto rbest) -> 4 blocks/CU.
__global__ __launch_bounds__(256, 2) void vq_main(const float* __restrict__ z,
                                                  const float* __restrict__ emb,
                                                  const unsigned short* __restrict__ eb,
                                                  const float* __restrict__ enorm,
                                                  float* __restrict__ out,
                                                  int* __restrict__ hist,
                                                  float* __restrict__ sums,
                                                  float* __restrict__ sum_zc) {
    __shared__ float zl[MTOK * SZZ];                        // 17408 B fp32 z, token-major
    __shared__ __align__(16) unsigned short ebl[ECH * 64];  // 16384 B bf16 chunk, swizzled
    __shared__ float enl[ECH];                              // 512 B enorm chunk
    __shared__ int   cand[MTOK][CAP];                       // 4096 B (zs-aliased at tail)
    __shared__ int   ccnt[MTOK];                            // 256 B
    __shared__ int   fi[MTOK];                              // 256 B
    __shared__ float rbest[4][MTOK];                        // 1024 B (wmin-aliased pre-pass2)
    __shared__ int   rbi[4][MTOK];                          // 1024 B

    const int tid = threadIdx.x;
    const int w = tid >> 6;             // wave 0..3 -> code quarter
    const int lane = tid & 63;
    const int n15 = lane & 15;
    const int q = lane >> 4;            // 0..3 (K-segment / token sub-row)
    const int t0 = blockIdx.x * MTOK;   // grid = 2048
    const int bb = t0 >> 15;
    const int s0 = t0 & (SP - 1);

    // ---- GLD staging (R13-verified): wave w stages ebl rows [w*32,w*32+32),
    //      linear dest, pre-swizzled source granule (l&7)^(l>>3) ----
    const int l3 = lane >> 3, l7 = lane & 7;
    const size_t gofs = (size_t)((l7 ^ l3) << 3);           // shorts
#define STAGE(cb)                                                             \
    {                                                                         \
        _Pragma("unroll")                                                     \
        for (int it = 0; it < 4; ++it) {                                      \
            const unsigned short* gs =                                        \
                eb + (size_t)((cb) + (w << 5) + it * 8 + l3) * CH + gofs;     \
            GLD16(gs, (char*)ebl + (w << 12) + (it << 10));                   \
        }                                                                     \
    }

    // ---- stage z tile token-major + ccnt (R13 prologue) ----
    {
        const float* zbase = z + ((size_t)bb * CH) * SP + s0;
#pragma unroll
        for (int j = 0; j < 4; ++j) {
            int idx = tid + j * 256;        // 0..1023
            int c = idx >> 4;
            int tq = idx & 15;
            float4 v = *(const float4*)(zbase + (size_t)c * SP + tq * 4);
            zl[(4 * tq + 0) * SZZ + c] = v.x;
            zl[(4 * tq + 1) * SZZ + c] = v.y;
            zl[(4 * tq + 2) * SZZ + c] = v.z;
            zl[(4 * tq + 3) * SZZ + c] = v.w;
        }
        if (tid < MTOK) ccnt[tid] = 0;
    }
    __syncthreads();

    // ---- persistent A fragments for ALL 4 token groups (layout per group
    //      identical to R13's single group -> same MFMA inputs) ----
    s16x8 A00, A01, A10, A11, A20, A21, A30, A31;
    {
        const float* zr0 = &zl[(0 * 16 + n15) * SZZ];
        const float* zr1 = &zl[(1 * 16 + n15) * SZZ];
        const float* zr2 = &zl[(2 * 16 + n15) * SZZ];
        const float* zr3 = &zl[(3 * 16 + n15) * SZZ];
        MK8(A00, zr0 + q * 8) MK8(A01, zr0 + 32 + q * 8)
        MK8(A10, zr1 + q * 8) MK8(A11, zr1 + 32 + q * 8)
        MK8(A20, zr2 + q * 8) MK8(A21, zr2 + 32 + q * 8)
        MK8(A30, zr3 + q * 8) MK8(A31, zr3 + 32 + q * 8)
    }
    const int gsw = q ^ (n15 & 7);     // swizzled read granule (row&7 == n15&7)

    // ---- pass 1: all 64 tokens vs this wave's code quarter ----
    float bm0[4] = {3.4e38f, 3.4e38f, 3.4e38f, 3.4e38f};
    float bm1[4] = {3.4e38f, 3.4e38f, 3.4e38f, 3.4e38f};
    float bm2[4] = {3.4e38f, 3.4e38f, 3.4e38f, 3.4e38f};
    float bm3[4] = {3.4e38f, 3.4e38f, 3.4e38f, 3.4e38f};
    for (int ch = 0; ch < NCHK; ++ch) {
        __syncthreads();   // prior chunk's ebl/enl reads done
        STAGE(ch * ECH)    // async DMA; drained by the next barrier's vmcnt(0)
        if (tid < ECH) enl[tid] = enorm[ch * ECH + tid];
        __syncthreads();
#pragma unroll
        for (int ct = 0; ct < 2; ++ct) {
            const int row = (w << 5) + ct * 16 + n15;   // this wave's quarter
            const s16x8* rowp = (const s16x8*)&ebl[(size_t)row << 6];
            s16x8 B0 = rowp[gsw];
            s16x8 B1 = rowp[gsw ^ 4];
            float en = enl[row];
            f32x4 a0 = {0.f, 0.f, 0.f, 0.f};
            f32x4 a1 = {0.f, 0.f, 0.f, 0.f};
            f32x4 a2 = {0.f, 0.f, 0.f, 0.f};
            f32x4 a3 = {0.f, 0.f, 0.f, 0.f};
            a0 = __builtin_amdgcn_mfma_f32_16x16x32_bf16(A00, B0, a0, 0, 0, 0);
            a0 = __builtin_amdgcn_mfma_f32_16x16x32_bf16(A01, B1, a0, 0, 0, 0);
            a1 = __builtin_amdgcn_mfma_f32_16x16x32_bf16(A10, B0, a1, 0, 0, 0);
            a1 = __builtin_amdgcn_mfma_f32_16x16x32_bf16(A11, B1, a1, 0, 0, 0);
            a2 = __builtin_amdgcn_mfma_f32_16x16x32_bf16(A20, B0, a2, 0, 0, 0);
            a2 = __builtin_amdgcn_mfma_f32_16x16x32_bf16(A21, B1, a2, 0, 0, 0);
            a3 = __builtin_amdgcn_mfma_f32_16x16x32_bf16(A30, B0, a3, 0, 0, 0);
            a3 = __builtin_amdgcn_mfma_f32_16x16x32_bf16(A31, B1, a3, 0, 0, 0);
#pragma unroll
            for (int r = 0; r < 4; ++r) {
                bm0[r] = fminf(bm0[r], fmaf(-2.f, a0[r], en));
                bm1[r] = fminf(bm1[r], fmaf(-2.f, a1[r], en));
                bm2[r] = fminf(bm2[r], fmaf(-2.f, a2[r], en));
                bm3[r] = fminf(bm3[r], fmaf(-2.f, a3[r], en));
            }
        }
    }
    // intra-wave butterfly over n15 (per group), then cross-wave LDS reduce.
    // exact min is order-independent -> thr values identical to R13's.
#pragma unroll
    for (int off = 1; off < 16; off <<= 1)
#pragma unroll
        for (int r = 0; r < 4; ++r) {
            bm0[r] = fminf(bm0[r], __shfl_xor(bm0[r], off));
            bm1[r] = fminf(bm1[r], __shfl_xor(bm1[r], off));
            bm2[r] = fminf(bm2[r], __shfl_xor(bm2[r], off));
            bm3[r] = fminf(bm3[r], __shfl_xor(bm3[r], off));
        }
    float* wmin = &rbest[0][0];        // 1024 B alias; dead until rescore
    if (n15 == 0) {
#pragma unroll
        for (int r = 0; r < 4; ++r) {
            wmin[w * 64 + 0 + 4 * q + r]  = bm0[r];
            wmin[w * 64 + 16 + 4 * q + r] = bm1[r];
            wmin[w * 64 + 32 + 4 * q + r] = bm2[r];
            wmin[w * 64 + 48 + 4 * q + r] = bm3[r];
        }
    }
    __syncthreads();
    float thr0[4], thr1[4], thr2[4], thr3[4];
#pragma unroll
    for (int r = 0; r < 4; ++r) {
        int i0 = 0 + 4 * q + r, i1 = 16 + 4 * q + r, i2 = 32 + 4 * q + r, i3 = 48 + 4 * q + r;
        thr0[r] = fminf(fminf(wmin[i0], wmin[64 + i0]), fminf(wmin[128 + i0], wmin[192 + i0])) + MARGIN;
        thr1[r] = fminf(fminf(wmin[i1], wmin[64 + i1]), fminf(wmin[128 + i1], wmin[192 + i1])) + MARGIN;
        thr2[r] = fminf(fminf(wmin[i2], wmin[64 + i2]), fminf(wmin[128 + i2], wmin[192 + i2])) + MARGIN;
        thr3[r] = fminf(fminf(wmin[i3], wmin[64 + i3]), fminf(wmin[128 + i3], wmin[192 + i3])) + MARGIN;
    }

    // ---- pass 2: identical compute, collect candidates within margin.
    //      chunk order 7,0..6: chunk 7 (ebl+enl) still resident -> no restage ----
    for (int cc = 0; cc < NCHK; ++cc) {
        int ch = (cc == 0) ? (NCHK - 1) : (cc - 1);
        if (cc) {
            __syncthreads();
            STAGE(ch * ECH)
            if (tid < ECH) enl[tid] = enorm[ch * ECH + tid];
            __syncthreads();
        }
#pragma unroll
        for (int ct = 0; ct < 2; ++ct) {
            const int row = (w << 5) + ct * 16 + n15;
            const s16x8* rowp = (const s16x8*)&ebl[(size_t)row << 6];
            s16x8 B0 = rowp[gsw];
            s16x8 B1 = rowp[gsw ^ 4];
            float en = enl[row];
            f32x4 a0 = {0.f, 0.f, 0.f, 0.f};
            f32x4 a1 = {0.f, 0.f, 0.f, 0.f};
            f32x4 a2 = {0.f, 0.f, 0.f, 0.f};
            f32x4 a3 = {0.f, 0.f, 0.f, 0.f};
            a0 = __builtin_amdgcn_mfma_f32_16x16x32_bf16(A00, B0, a0, 0, 0, 0);
            a0 = __builtin_amdgcn_mfma_f32_16x16x32_bf16(A01, B1, a0, 0, 0, 0);
            a1 = __builtin_amdgcn_mfma_f32_16x16x32_bf16(A10, B0, a1, 0, 0, 0);
            a1 = __builtin_amdgcn_mfma_f32_16x16x32_bf16(A11, B1, a1, 0, 0, 0);
            a2 = __builtin_amdgcn_mfma_f32_16x16x32_bf16(A20, B0, a2, 0, 0, 0);
            a2 = __builtin_amdgcn_mfma_f32_16x16x32_bf16(A21, B1, a2, 0, 0, 0);
            a3 = __builtin_amdgcn_mfma_f32_16x16x32_bf16(A30, B0, a3, 0, 0, 0);
            a3 = __builtin_amdgcn_mfma_f32_16x16x32_bf16(A31, B1, a3, 0, 0, 0);
            int code = ch * ECH + row;
#pragma unroll
            for (int r = 0; r < 4; ++r) {
                float d0 = fmaf(-2.f, a0[r], en);
                if (d0 <= thr0[r]) {
                    int t = 0 + 4 * q + r;
                    int pos = atomicAdd(&ccnt[t], 1);
                    if (pos < CAP) cand[t][pos] = code;
                }
                float d1 = fmaf(-2.f, a1[r], en);
                if (d1 <= thr1[r]) {
                    int t = 16 + 4 * q + r;
                    int pos = atomicAdd(&ccnt[t], 1);
                    if (pos < CAP) cand[t][pos] = code;
                }
                float d2 = fmaf(-2.f, a2[r], en);
                if (d2 <= thr2[r]) {
                    int t = 32 + 4 * q + r;
                    int pos = atomicAdd(&ccnt[t], 1);
                    if (pos < CAP) cand[t][pos] = code;
                }
                float d3 = fmaf(-2.f, a3[r], en);
                if (d3 <= thr3[r]) {
                    int t = 48 + 4 * q + r;
                    int pos = atomicAdd(&ccnt[t], 1);
                    if (pos < CAP) cand[t][pos] = code;
                }
            }
        }
    }
    __syncthreads();

    // ---- exact fp32 rescore, 4x-parallel (R13-verified) ----
    {
        const int t = tid & 63;
        const int part = tid >> 6;
        const float* zrow = &zl[t * SZZ];
        int cnt = ccnt[t];
        float best = 3.4e38f;
        int bi = 0;
        if (cnt <= CAP) {
            for (int j = part; j < cnt; j += 4) {
                int c = cand[t][j];
                float d = exact_dist(zrow, emb, enorm, c);
                if (d < best || (d == best && c < bi)) { best = d; bi = c; }
            }
        } else {   // overflow fallback (rare at CAP=16): strided exact scan
            for (int c = part; c < KC; c += 4) {
                float d = exact_dist(zrow, emb, enorm, c);
                if (d < best || (d == best && c < bi)) { best = d; bi = c; }
            }
        }
        rbest[part][t] = best;
        rbi[part][t] = bi;
    }
    __syncthreads();
    if (tid < MTOK) {
        float best = rbest[0][tid];
        int bi = rbi[0][tid];
#pragma unroll
        for (int p = 1; p < 4; ++p) {
            float b = rbest[p][tid];
            int i = rbi[p][tid];
            if (b < best || (b == best && i < bi)) { best = b; bi = i; }
        }
        fi[tid] = bi;
        out[OFF_IDX + t0 + tid] = (float)bi;   // coalesced
        atomicAdd(&hist[bi], 1);
    }
    __syncthreads();

    // ---- z_q epilogue: z + (e[code] - z), coalesced per channel ----
#pragma unroll
    for (int j = 0; j < 16; ++j) {
        int idx = tid + j * 256;   // 0..4095
        int c = idx >> 6;
        int t = idx & 63;
        int code = fi[t];
        float ev = emb[(size_t)code * CH + c];   // L1/L2-hot gather
        float zv = zl[t * SZZ + c];
        out[OFF_ZQ + ((size_t)bb * CH + c) * SP + s0 + t] = zv + (ev - zv);
    }

    // ---- z statistics at kernel tail (zs aliased onto dead cand, R12/R13) ----
    {
        float* zs1 = reinterpret_cast<float*>(cand);   // 2048 B needed <= 4096 B
        float* zs2 = zs1 + 256;
        int c = tid >> 2, qq = tid & 3;
        float s1 = 0.f, s2 = 0.f;
        for (int tt = 0; tt < 16; ++tt) {
            float v = zl[(qq * 16 + tt) * SZZ + c];
            s1 += v;
            s2 = fmaf(v, v, s2);
        }
        zs1[tid] = s1;
        zs2[tid] = s2;
        __syncthreads();
        if (tid < 64) {
            float a = zs1[4 * tid] + zs1[4 * tid + 1] + zs1[4 * tid + 2] + zs1[4 * tid + 3];
            atomicAdd(&sum_zc[tid], a);
            float bsum = zs2[4 * tid] + zs2[4 * tid + 1] + zs2[4 * tid + 2] + zs2[4 * tid + 3];
            for (int off = 32; off; off >>= 1) bsum += __shfl_down(bsum, off);
            if (tid == 0) atomicAdd(&sums[0], bsum);
        }
    }
#undef STAGE
}

__global__ __launch_bounds__(1024) void finalize(const int* __restrict__ hist,
                                                 const float* __restrict__ sums,
                                                 const float* __restrict__ sum_zc,
                                                 const float* __restrict__ sum_ec,
                                                 float* __restrict__ out) {
    __shared__ float red[1024];
    int k = threadIdx.x;
    float p = (float)hist[k] * (1.0f / (float)NTOK);
    red[k] = p * logf(p + 1e-10f);
    __syncthreads();
    for (int off = 512; off; off >>= 1) {
        if (k < off) red[k] += red[k + off];
        __syncthreads();
    }
    if (k == 0) {
        out[OFF_PERP] = expf(-red[0]);
        out[OFF_LOSS] = 0.f;
        double dot = 0.0;
        for (int c = 0; c < CH; ++c) dot += (double)sum_zc[c] * (double)sum_ec[c];
        double mean = ((double)KC * (double)sums[0] + (double)NTOK * (double)sums[1] - 2.0 * dot)
                      / ((double)NTOK * (double)KC);
        out[OFF_MEAN] = (float)mean;
    }
}

extern "C" void kernel_launch(void* const* d_in, const int* in_sizes, int n_in,
                              void* d_out, int out_size, void* d_ws, size_t ws_size,
                              hipStream_t stream) {
    const float* z   = (const float*)d_in[0];
    const float* emb = (const float*)d_in[1];
    float* out = (float*)d_out;

    int*            hist   = (int*)d_ws;
    float*          sums   = (float*)d_ws + 1024;   // [0]=sum_z2 [1]=sum_e2
    float*          sum_zc = (float*)d_ws + 1026;
    float*          sum_ec = (float*)d_ws + 1090;
    float*          enorm  = (float*)d_ws + 1154;
    unsigned short* eb     = (unsigned short*)((int*)d_ws + 4096);  // 128 KB bf16 table

    prep<<<13, 256, 0, stream>>>(emb, hist, sums, sum_zc, sum_ec, enorm, eb);
    vq_main<<<NTOK / MTOK, 256, 0, stream>>>(z, emb, eb, enorm, out, hist, sums, sum_zc);
    finalize<<<1, 1024, 0, stream>>>(hist, sums, sum_zc, sum_ec, out);
}